// Round 5
// baseline (139.883 us; speedup 1.0000x reference)
//
#include <hip/hip_runtime.h>
#include <cstdint>
#include <cstddef>

#define BB 32
#define NN 4096
#define DD 256
#define KK 16

constexpr float FEPS = 1e-12f;

__device__ __forceinline__ float dot4(float4 a, float4 b) {
  return a.x*b.x + a.y*b.y + a.z*b.z + a.w*b.w;
}

// ---------------------------------------------------------------------------
// Fused kernel, TILE tokens per block, 256 threads.
// Phase A: thread = (token, k-group): KPT logits from LDS-staged x + scalar W.
// Phase B: wave = (k-octet, token-half): outer-product accumulate (2x reads).
// Combine halves in LDS; per-block partial (or atomic) output.
// ---------------------------------------------------------------------------
template <int TILE>
__global__ __launch_bounds__(256, 6) void fused_kernel(
    const float* __restrict__ x, const int* __restrict__ mask,
    const float* __restrict__ W, const float* __restrict__ bias,
    float* __restrict__ outv, float* __restrict__ outs, int partial_mode)
{
  constexpr int NG   = 256 / TILE;      // k-groups (thread layers)
  constexpr int KPT  = KK / NG;         // k per thread in Phase A
  constexpr int SW   = TILE / 32;       // staging sweeps per chunk
  constexpr int TPW  = TILE / 2;        // tokens per wave in Phase B
  constexpr int WPG  = 4 / NG;          // waves per k-group
  constexpr int SRAW = (TILE * 36 > 4096) ? TILE * 36 : 4096;
  constexpr int TPBAT = NN / TILE;

  __shared__ float sraw[SRAW];          // xs[TILE][9] float4s; later cmb[16][256]
  __shared__ float al[TILE][KK];
  __shared__ float psum[TILE][NG];
  __shared__ float asacc[WPG][KK];

  float4* xs4 = reinterpret_cast<float4*>(sraw);

  const int tid  = threadIdx.x;
  const int lane = tid & 63;
  const int wave = tid >> 6;
  const int tok  = tid & (TILE - 1);
  const int kg   = __builtin_amdgcn_readfirstlane(tid / TILE);
  const int slot = __builtin_amdgcn_readfirstlane(wave & (WPG - 1));

  const int tile = blockIdx.x;
  const int b    = tile / TPBAT;
  const int n0   = (tile % TPBAT) * TILE;

  const float4* xb4 = reinterpret_cast<const float4*>(x + ((size_t)b*NN + n0)*DD);
  const int*    mb  = mask + (size_t)b*NN + n0;

  // ---------------- Phase A: KPT logits per thread ------------------------
  float part[KPT];
#pragma unroll
  for (int q = 0; q < KPT; ++q) part[q] = bias[kg * KPT + q];

  const int st = tid >> 3;              // staging token base
  const int sj = tid & 7;               // staging col

#pragma unroll 1
  for (int c = 0; c < 8; ++c) {         // 8 chunks of 32 dims
#pragma unroll
    for (int l = 0; l < SW; ++l) {
      const int t = st + l * 32;
      xs4[t * 9 + sj] = xb4[(size_t)t * 64 + c * 8 + sj];  // pad-9: conflict-free
    }
    __syncthreads();
#pragma unroll
    for (int j = 0; j < 8; ++j) {
      const float4 xv = xs4[tok * 9 + j];                  // pad-9: conflict-free
      const float* Wc = W + c * 32 + j * 4;
#pragma unroll
      for (int q = 0; q < KPT; ++q) {
        const float4 wv = *reinterpret_cast<const float4*>(Wc + (kg * KPT + q) * DD);
        part[q] += dot4(xv, wv);
      }
    }
    __syncthreads();
  }

  // masked softmax across NG thread-layers via psum exchange
  float e[KPT], pexp = 0.f;
#pragma unroll
  for (int q = 0; q < KPT; ++q) { e[q] = __expf(part[q]); pexp += e[q]; }
  psum[tok][kg] = pexp;
  __syncthreads();
  float a[KPT];
  {
    float denom = 0.f;
#pragma unroll
    for (int g = 0; g < NG; ++g) denom += psum[tok][g];
    const float r = mb[tok] ? (1.0f / denom) : 0.0f;
#pragma unroll
    for (int q = 0; q < KPT; ++q) a[q] = e[q] * r;
#pragma unroll
    for (int q4 = 0; q4 < KPT; q4 += 4)
      *reinterpret_cast<float4*>(&al[tok][kg * KPT + q4]) =
          make_float4(a[q4], a[q4+1], a[q4+2], a[q4+3]);
  }

  // asum: butterfly over 64 lanes (= 64 distinct tokens per wave)
  {
    float red[KPT];
#pragma unroll
    for (int q = 0; q < KPT; ++q) red[q] = a[q];
#pragma unroll
    for (int off = 32; off >= 1; off >>= 1)
#pragma unroll
      for (int q = 0; q < KPT; ++q) red[q] += __shfl_xor(red[q], off);
    if (lane == 0)
#pragma unroll
      for (int q = 0; q < KPT; ++q) asacc[slot][kg * KPT + q] = red[q];
  }
  __syncthreads();

  // ------ Phase B: wave = (k-octet kh, token-half th) ---------------------
  const int kh = wave >> 1;
  const int th = wave & 1;

  float4 acc[8];
#pragma unroll
  for (int i = 0; i < 8; ++i) acc[i] = make_float4(0.f, 0.f, 0.f, 0.f);

  const float4* xw = xb4 + (size_t)(th * TPW) * 64 + lane;

#pragma unroll 4
  for (int t = 0; t < TPW; ++t) {
    const float4 xv  = xw[(size_t)t * 64];
    const float4 av0 = *reinterpret_cast<const float4*>(&al[th * TPW + t][kh * 8 + 0]);
    const float4 av1 = *reinterpret_cast<const float4*>(&al[th * TPW + t][kh * 8 + 4]);
    acc[0].x += av0.x*xv.x; acc[0].y += av0.x*xv.y; acc[0].z += av0.x*xv.z; acc[0].w += av0.x*xv.w;
    acc[1].x += av0.y*xv.x; acc[1].y += av0.y*xv.y; acc[1].z += av0.y*xv.z; acc[1].w += av0.y*xv.w;
    acc[2].x += av0.z*xv.x; acc[2].y += av0.z*xv.y; acc[2].z += av0.z*xv.z; acc[2].w += av0.z*xv.w;
    acc[3].x += av0.w*xv.x; acc[3].y += av0.w*xv.y; acc[3].z += av0.w*xv.z; acc[3].w += av0.w*xv.w;
    acc[4].x += av1.x*xv.x; acc[4].y += av1.x*xv.y; acc[4].z += av1.x*xv.z; acc[4].w += av1.x*xv.w;
    acc[5].x += av1.y*xv.x; acc[5].y += av1.y*xv.y; acc[5].z += av1.y*xv.z; acc[5].w += av1.y*xv.w;
    acc[6].x += av1.z*xv.x; acc[6].y += av1.z*xv.y; acc[6].z += av1.z*xv.z; acc[6].w += av1.z*xv.w;
    acc[7].x += av1.w*xv.x; acc[7].y += av1.w*xv.y; acc[7].z += av1.w*xv.z; acc[7].w += av1.w*xv.w;
  }

  // combine token-halves: th=1 writes, th=0 adds (sraw reused as cmb[16][256])
  float4* cmb4 = reinterpret_cast<float4*>(sraw);
  if (th == 1) {
#pragma unroll
    for (int i = 0; i < 8; ++i) cmb4[(kh * 8 + i) * 64 + lane] = acc[i];
  }
  __syncthreads();
  if (th == 0) {
#pragma unroll
    for (int i = 0; i < 8; ++i) {
      const float4 v = cmb4[(kh * 8 + i) * 64 + lane];
      acc[i].x += v.x; acc[i].y += v.y; acc[i].z += v.z; acc[i].w += v.w;
    }
  }

  // ------------- output ----------------------------------------------------
  if (partial_mode) {
    if (th == 0) {
      float4* dst = reinterpret_cast<float4*>(outv + (size_t)tile * KK * DD);
#pragma unroll
      for (int i = 0; i < 8; ++i) dst[(kh * 8 + i) * 64 + lane] = acc[i];
    }
    if (tid < KK) {
      float s = 0.f;
#pragma unroll
      for (int sl = 0; sl < WPG; ++sl) s += asacc[sl][tid];
      outs[tile * KK + tid] = s;
    }
  } else {
    if (th == 0) {
      float* vb = outv + (size_t)b * KK * DD;
#pragma unroll
      for (int i = 0; i < 8; ++i) {
        float* p = vb + (kh * 8 + i) * DD + 4 * lane;
        atomicAdd(p + 0, acc[i].x);
        atomicAdd(p + 1, acc[i].y);
        atomicAdd(p + 2, acc[i].z);
        atomicAdd(p + 3, acc[i].w);
      }
    }
    if (tid < KK) {
      float s = 0.f;
#pragma unroll
      for (int sl = 0; sl < WPG; ++sl) s += asacc[sl][tid];
      atomicAdd(&outs[b * KK + tid], s);
    }
  }
}

// ---------------------------------------------------------------------------
// Finalize A (BB*4 blocks x 256 thr): block (b, kq). Sum slices, subtract
// asum*c, write centered vlad to vtmp and per-k sum-of-squares to ssbuf.
// ---------------------------------------------------------------------------
__global__ __launch_bounds__(256) void finalizeA_kernel(
    const float* __restrict__ pv, const float* __restrict__ ps,
    const float* __restrict__ cent, float* __restrict__ vtmp,
    float* __restrict__ ssbuf, int nslice)
{
  const int b    = blockIdx.x >> 2;
  const int kq   = blockIdx.x & 3;
  const int d    = threadIdx.x;
  const int lane = d & 63;
  const int w    = d >> 6;

  __shared__ float redA[4][4];

  float v[4];
#pragma unroll
  for (int kk = 0; kk < 4; ++kk) {
    const int k = kq * 4 + kk;
    float acc = 0.f, ssum = 0.f;
    for (int s = 0; s < nslice; ++s) {
      acc  += pv[((size_t)(b * nslice + s) * KK + k) * DD + d];
      ssum += ps[(b * nslice + s) * KK + k];
    }
    v[kk] = acc - ssum * cent[k * DD + d];
    vtmp[((size_t)b * KK + k) * DD + d] = v[kk];
  }

#pragma unroll
  for (int kk = 0; kk < 4; ++kk) {
    float p = v[kk] * v[kk];
#pragma unroll
    for (int off = 32; off >= 1; off >>= 1) p += __shfl_xor(p, off);
    if (lane == 0) redA[kk][w] = p;
  }
  __syncthreads();

  if (d < 4) {
    const float ss = redA[d][0] + redA[d][1] + redA[d][2] + redA[d][3];
    ssbuf[b * KK + kq * 4 + d] = ss;
  }
}

// ---------------------------------------------------------------------------
// Finalize B (BB blocks x 1024 thr): intra-cluster + global L2 normalize.
// ---------------------------------------------------------------------------
__global__ __launch_bounds__(1024) void finalizeB_kernel(
    const float* __restrict__ vtmp, const float* __restrict__ ssbuf,
    float* __restrict__ out)
{
  const int b    = blockIdx.x;
  const int tid  = threadIdx.x;
  const int d    = tid & 255;
  const int kq   = tid >> 8;        // 0..3
  const int lane = tid & 63;
  const int w    = tid >> 6;        // 0..15

  __shared__ float redB[16];
  __shared__ float gsh;

  float u[4];
  float p2 = 0.f;
#pragma unroll
  for (int kk = 0; kk < 4; ++kk) {
    const int k = kq * 4 + kk;
    const float rk = 1.0f / fmaxf(sqrtf(ssbuf[b * KK + k]), FEPS);
    u[kk] = vtmp[((size_t)b * KK + k) * DD + d] * rk;
    p2 += u[kk] * u[kk];
  }
#pragma unroll
  for (int off = 32; off >= 1; off >>= 1) p2 += __shfl_xor(p2, off);
  if (lane == 0) redB[w] = p2;
  __syncthreads();

  if (tid == 0) {
    float g = 0.f;
#pragma unroll
    for (int i = 0; i < 16; ++i) g += redB[i];
    gsh = 1.0f / fmaxf(sqrtf(g), FEPS);
  }
  __syncthreads();

  const float g = gsh;
#pragma unroll
  for (int kk = 0; kk < 4; ++kk) {
    const int k = kq * 4 + kk;
    out[(size_t)b * KK * DD + k * DD + d] = u[kk] * g;
  }
}

extern "C" void kernel_launch(void* const* d_in, const int* in_sizes, int n_in,
                              void* d_out, int out_size, void* d_ws, size_t ws_size,
                              hipStream_t stream) {
  const float* x    = (const float*)d_in[0];
  const int*   mask = (const int*)d_in[1];
  const float* W    = (const float*)d_in[2];
  const float* bias = (const float*)d_in[3];
  const float* cent = (const float*)d_in[4];
  float* out = (float*)d_out;

  const size_t vtmpN  = (size_t)BB * KK * DD;    // centered vlad
  const size_t ssN    = (size_t)BB * KK;

  const size_t t64    = (size_t)BB * (NN / 64);   // 2048 tiles
  const size_t t128   = (size_t)BB * (NN / 128);  // 1024 tiles
  const size_t need64  = (t64  * KK * DD + t64  * KK + vtmpN + ssN) * sizeof(float);
  const size_t need128 = (t128 * KK * DD + t128 * KK + vtmpN + ssN) * sizeof(float);
  const size_t needAtm = (vtmpN + ssN + vtmpN + ssN) * sizeof(float);

  if (ws_size >= need64) {
    float* pv    = (float*)d_ws;
    float* ps    = pv + t64 * KK * DD;
    float* vtmp  = ps + t64 * KK;
    float* ssbuf = vtmp + vtmpN;
    fused_kernel<64><<<(int)t64, 256, 0, stream>>>(x, mask, W, bias, pv, ps, 1);
    finalizeA_kernel<<<BB * 4, 256, 0, stream>>>(pv, ps, cent, vtmp, ssbuf, NN / 64);
    finalizeB_kernel<<<BB, 1024, 0, stream>>>(vtmp, ssbuf, out);
  } else if (ws_size >= need128) {
    float* pv    = (float*)d_ws;
    float* ps    = pv + t128 * KK * DD;
    float* vtmp  = ps + t128 * KK;
    float* ssbuf = vtmp + vtmpN;
    fused_kernel<128><<<(int)t128, 256, 0, stream>>>(x, mask, W, bias, pv, ps, 1);
    finalizeA_kernel<<<BB * 4, 256, 0, stream>>>(pv, ps, cent, vtmp, ssbuf, NN / 128);
    finalizeB_kernel<<<BB, 1024, 0, stream>>>(vtmp, ssbuf, out);
  } else {
    (void)needAtm;
    float* vacc  = (float*)d_ws;                 // [BB][KK][DD]
    float* sacc  = vacc + vtmpN;                 // [BB][KK]
    float* vtmp  = sacc + ssN;
    float* ssbuf = vtmp + vtmpN;
    hipMemsetAsync(d_ws, 0, (vtmpN + ssN) * sizeof(float), stream);
    fused_kernel<64><<<(int)t64, 256, 0, stream>>>(x, mask, W, bias, vacc, sacc, 0);
    finalizeA_kernel<<<BB * 4, 256, 0, stream>>>(vacc, sacc, cent, vtmp, ssbuf, 1);
    finalizeB_kernel<<<BB, 1024, 0, stream>>>(vtmp, ssbuf, out);
  }
}

// Round 6
// 95.553 us; speedup vs baseline: 1.4639x; 1.4639x over previous
//
#include <hip/hip_runtime.h>
#include <cstdint>
#include <cstddef>

#define BB 32
#define NN 4096
#define DD 256
#define KK 16

constexpr float FEPS = 1e-12f;

__device__ __forceinline__ float dot4(float4 a, float4 b) {
  return a.x*b.x + a.y*b.y + a.z*b.z + a.w*b.w;
}

// ---------------------------------------------------------------------------
// Fused kernel, TILE tokens per block, 256 threads.
// Phase A: thread = (token, k-group): KPT logits; x staged via DOUBLE-BUFFERED
//          LDS chunks (pad-9 conflict-free), W via scalar loads.
// Phase B: wave = (k-octet, token-half): outer-product accumulate.
// ---------------------------------------------------------------------------
template <int TILE>
__global__ __launch_bounds__(256, (TILE == 64 ? 6 : 3)) void fused_kernel(
    const float* __restrict__ x, const int* __restrict__ mask,
    const float* __restrict__ W, const float* __restrict__ bias,
    float* __restrict__ outv, float* __restrict__ outs, int partial_mode)
{
  constexpr int NG   = 256 / TILE;      // k-groups (thread layers)
  constexpr int KPT  = KK / NG;         // k per thread in Phase A
  constexpr int SW   = TILE / 32;       // staging loads per thread per chunk
  constexpr int TPW  = TILE / 2;        // tokens per wave in Phase B
  constexpr int WPG  = 4 / NG;          // waves per k-group
  constexpr int XSN  = TILE * 9;        // float4 per staging buffer
  constexpr int TPBAT = NN / TILE;

  __shared__ float4 xs4[2][XSN];        // double-buffered x staging; cmb later
  __shared__ float  al[TILE][KK];
  __shared__ float  psum[TILE][NG];
  __shared__ float  asacc[WPG][KK];

  const int tid  = threadIdx.x;
  const int lane = tid & 63;
  const int wave = tid >> 6;
  const int tok  = tid & (TILE - 1);
  const int kg   = __builtin_amdgcn_readfirstlane(tid / TILE);
  const int slot = __builtin_amdgcn_readfirstlane(wave & (WPG - 1));

  const int tile = blockIdx.x;
  const int b    = tile / TPBAT;
  const int n0   = (tile % TPBAT) * TILE;

  const float4* xb4 = reinterpret_cast<const float4*>(x + ((size_t)b*NN + n0)*DD);
  const int*    mb  = mask + (size_t)b*NN + n0;

  // ---------------- Phase A: KPT logits per thread, dbuf staging ----------
  float part[KPT];
#pragma unroll
  for (int q = 0; q < KPT; ++q) part[q] = bias[kg * KPT + q];

  const int st = tid >> 3;              // staging token base
  const int sj = tid & 7;               // staging col

  // prologue: stage chunk 0 into buffer 0
  {
    float4 pre[SW];
#pragma unroll
    for (int l = 0; l < SW; ++l)
      pre[l] = xb4[(size_t)(st + l * 32) * 64 + sj];
#pragma unroll
    for (int l = 0; l < SW; ++l)
      xs4[0][(st + l * 32) * 9 + sj] = pre[l];
  }

#pragma unroll 1
  for (int c = 0; c < 8; ++c) {         // 8 chunks of 32 dims
    __syncthreads();                    // chunk c staged; old buffer free
    const int cur = c & 1;

    float4 nxt[SW];
    if (c < 7) {                        // issue chunk c+1 loads (overlap)
#pragma unroll
      for (int l = 0; l < SW; ++l)
        nxt[l] = xb4[(size_t)(st + l * 32) * 64 + (c + 1) * 8 + sj];
    }

#pragma unroll
    for (int j = 0; j < 8; ++j) {       // compute on chunk c
      const float4 xv = xs4[cur][tok * 9 + j];
      const float* Wc = W + c * 32 + j * 4;
#pragma unroll
      for (int q = 0; q < KPT; ++q) {
        const float4 wv = *reinterpret_cast<const float4*>(Wc + (kg * KPT + q) * DD);
        part[q] += dot4(xv, wv);
      }
    }

    if (c < 7) {                        // land chunk c+1 into other buffer
#pragma unroll
      for (int l = 0; l < SW; ++l)
        xs4[cur ^ 1][(st + l * 32) * 9 + sj] = nxt[l];
    }
  }

  // masked softmax across NG thread-layers via psum exchange
  float e[KPT], pexp = 0.f;
#pragma unroll
  for (int q = 0; q < KPT; ++q) { e[q] = __expf(part[q]); pexp += e[q]; }
  psum[tok][kg] = pexp;
  __syncthreads();
  float a[KPT];
  {
    float denom = 0.f;
#pragma unroll
    for (int g = 0; g < NG; ++g) denom += psum[tok][g];
    const float r = mb[tok] ? (1.0f / denom) : 0.0f;
#pragma unroll
    for (int q = 0; q < KPT; ++q) a[q] = e[q] * r;
#pragma unroll
    for (int q4 = 0; q4 < KPT; q4 += 4)
      *reinterpret_cast<float4*>(&al[tok][kg * KPT + q4]) =
          make_float4(a[q4], a[q4+1], a[q4+2], a[q4+3]);
  }

  // asum: butterfly over 64 lanes (= 64 distinct tokens per wave)
  {
    float red[KPT];
#pragma unroll
    for (int q = 0; q < KPT; ++q) red[q] = a[q];
#pragma unroll
    for (int off = 32; off >= 1; off >>= 1)
#pragma unroll
      for (int q = 0; q < KPT; ++q) red[q] += __shfl_xor(red[q], off);
    if (lane == 0)
#pragma unroll
      for (int q = 0; q < KPT; ++q) asacc[slot][kg * KPT + q] = red[q];
  }
  __syncthreads();

  // ------ Phase B: wave = (k-octet kh, token-half th) ---------------------
  const int kh = wave >> 1;
  const int th = wave & 1;

  float4 acc[8];
#pragma unroll
  for (int i = 0; i < 8; ++i) acc[i] = make_float4(0.f, 0.f, 0.f, 0.f);

  const float4* xw = xb4 + (size_t)(th * TPW) * 64 + lane;

#pragma unroll 4
  for (int t = 0; t < TPW; ++t) {
    const float4 xv  = xw[(size_t)t * 64];
    const float4 av0 = *reinterpret_cast<const float4*>(&al[th * TPW + t][kh * 8 + 0]);
    const float4 av1 = *reinterpret_cast<const float4*>(&al[th * TPW + t][kh * 8 + 4]);
    acc[0].x += av0.x*xv.x; acc[0].y += av0.x*xv.y; acc[0].z += av0.x*xv.z; acc[0].w += av0.x*xv.w;
    acc[1].x += av0.y*xv.x; acc[1].y += av0.y*xv.y; acc[1].z += av0.y*xv.z; acc[1].w += av0.y*xv.w;
    acc[2].x += av0.z*xv.x; acc[2].y += av0.z*xv.y; acc[2].z += av0.z*xv.z; acc[2].w += av0.z*xv.w;
    acc[3].x += av0.w*xv.x; acc[3].y += av0.w*xv.y; acc[3].z += av0.w*xv.z; acc[3].w += av0.w*xv.w;
    acc[4].x += av1.x*xv.x; acc[4].y += av1.x*xv.y; acc[4].z += av1.x*xv.z; acc[4].w += av1.x*xv.w;
    acc[5].x += av1.y*xv.x; acc[5].y += av1.y*xv.y; acc[5].z += av1.y*xv.z; acc[5].w += av1.y*xv.w;
    acc[6].x += av1.z*xv.x; acc[6].y += av1.z*xv.y; acc[6].z += av1.z*xv.z; acc[6].w += av1.z*xv.w;
    acc[7].x += av1.w*xv.x; acc[7].y += av1.w*xv.y; acc[7].z += av1.w*xv.z; acc[7].w += av1.w*xv.w;
  }

  // combine token-halves: th=1 writes, th=0 adds (xs4 reused as cmb[16][256])
  float4* cmb4 = reinterpret_cast<float4*>(xs4);
  if (th == 1) {
#pragma unroll
    for (int i = 0; i < 8; ++i) cmb4[(kh * 8 + i) * 64 + lane] = acc[i];
  }
  __syncthreads();
  if (th == 0) {
#pragma unroll
    for (int i = 0; i < 8; ++i) {
      const float4 v = cmb4[(kh * 8 + i) * 64 + lane];
      acc[i].x += v.x; acc[i].y += v.y; acc[i].z += v.z; acc[i].w += v.w;
    }
  }

  // ------------- output ----------------------------------------------------
  if (partial_mode) {
    if (th == 0) {
      float4* dst = reinterpret_cast<float4*>(outv + (size_t)tile * KK * DD);
#pragma unroll
      for (int i = 0; i < 8; ++i) dst[(kh * 8 + i) * 64 + lane] = acc[i];
    }
    if (tid < KK) {
      float s = 0.f;
#pragma unroll
      for (int sl = 0; sl < WPG; ++sl) s += asacc[sl][tid];
      outs[tile * KK + tid] = s;
    }
  } else {
    if (th == 0) {
      float* vb = outv + (size_t)b * KK * DD;
#pragma unroll
      for (int i = 0; i < 8; ++i) {
        float* p = vb + (kh * 8 + i) * DD + 4 * lane;
        atomicAdd(p + 0, acc[i].x);
        atomicAdd(p + 1, acc[i].y);
        atomicAdd(p + 2, acc[i].z);
        atomicAdd(p + 3, acc[i].w);
      }
    }
    if (tid < KK) {
      float s = 0.f;
#pragma unroll
      for (int sl = 0; sl < WPG; ++sl) s += asacc[sl][tid];
      atomicAdd(&outs[b * KK + tid], s);
    }
  }
}

// ---------------------------------------------------------------------------
// Finalize A (BB*KK blocks x 256 thr): block = (b,k), thread = dim d.
// Slice-sum (8-wide unrolled, independent accumulators), ssum block-reduced
// once, centered value to vtmp, per-k sum-of-squares to ssbuf.
// ---------------------------------------------------------------------------
__global__ __launch_bounds__(256) void finalizeA_kernel(
    const float* __restrict__ pv, const float* __restrict__ ps,
    const float* __restrict__ cent, float* __restrict__ vtmp,
    float* __restrict__ ssbuf, int nslice)
{
  const int blk  = blockIdx.x;
  const int b    = blk >> 4;
  const int k    = blk & 15;
  const int d    = threadIdx.x;
  const int lane = d & 63;
  const int w    = d >> 6;

  __shared__ float sred[4];
  __shared__ float qred[4];
  __shared__ float ssh;

  // ssum = sum_s ps[(b*ns+s)*KK + k], block-reduced once
  {
    float pval = 0.f;
    for (int s = d; s < nslice; s += 256)
      pval += ps[(size_t)(b * nslice + s) * KK + k];
#pragma unroll
    for (int off = 32; off >= 1; off >>= 1) pval += __shfl_xor(pval, off);
    if (lane == 0) sred[w] = pval;
  }
  __syncthreads();
  const float ssum = sred[0] + sred[1] + sred[2] + sred[3];

  // slice-sum of pv with 8 independent accumulators
  const float* base = pv + ((size_t)b * nslice * KK + k) * DD + d;
  float a0=0.f,a1=0.f,a2=0.f,a3=0.f,a4=0.f,a5=0.f,a6=0.f,a7=0.f;
  int s = 0;
  for (; s + 8 <= nslice; s += 8) {
    a0 += base[(size_t)(s+0) * KK * DD];
    a1 += base[(size_t)(s+1) * KK * DD];
    a2 += base[(size_t)(s+2) * KK * DD];
    a3 += base[(size_t)(s+3) * KK * DD];
    a4 += base[(size_t)(s+4) * KK * DD];
    a5 += base[(size_t)(s+5) * KK * DD];
    a6 += base[(size_t)(s+6) * KK * DD];
    a7 += base[(size_t)(s+7) * KK * DD];
  }
  for (; s < nslice; ++s) a0 += base[(size_t)s * KK * DD];
  const float v = ((a0+a1)+(a2+a3)) + ((a4+a5)+(a6+a7)) - ssum * cent[k * DD + d];

  vtmp[((size_t)b * KK + k) * DD + d] = v;

  // per-(b,k) sum of squares
  {
    float p = v * v;
#pragma unroll
    for (int off = 32; off >= 1; off >>= 1) p += __shfl_xor(p, off);
    if (lane == 0) qred[w] = p;
  }
  __syncthreads();
  if (d == 0) ssh = qred[0] + qred[1] + qred[2] + qred[3];
  __syncthreads();
  if (d == 0) ssbuf[blk] = ssh;
}

// ---------------------------------------------------------------------------
// Finalize B (BB blocks x 1024 thr): intra-cluster + global L2 normalize.
// ---------------------------------------------------------------------------
__global__ __launch_bounds__(1024) void finalizeB_kernel(
    const float* __restrict__ vtmp, const float* __restrict__ ssbuf,
    float* __restrict__ out)
{
  const int b    = blockIdx.x;
  const int tid  = threadIdx.x;
  const int d    = tid & 255;
  const int kq   = tid >> 8;        // 0..3
  const int lane = tid & 63;
  const int w    = tid >> 6;        // 0..15

  __shared__ float redB[16];
  __shared__ float gsh;

  float u[4];
  float p2 = 0.f;
#pragma unroll
  for (int kk = 0; kk < 4; ++kk) {
    const int k = kq * 4 + kk;
    const float rk = 1.0f / fmaxf(sqrtf(ssbuf[b * KK + k]), FEPS);
    u[kk] = vtmp[((size_t)b * KK + k) * DD + d] * rk;
    p2 += u[kk] * u[kk];
  }
#pragma unroll
  for (int off = 32; off >= 1; off >>= 1) p2 += __shfl_xor(p2, off);
  if (lane == 0) redB[w] = p2;
  __syncthreads();

  if (tid == 0) {
    float g = 0.f;
#pragma unroll
    for (int i = 0; i < 16; ++i) g += redB[i];
    gsh = 1.0f / fmaxf(sqrtf(g), FEPS);
  }
  __syncthreads();

  const float g = gsh;
#pragma unroll
  for (int kk = 0; kk < 4; ++kk) {
    const int k = kq * 4 + kk;
    out[(size_t)b * KK * DD + k * DD + d] = u[kk] * g;
  }
}

extern "C" void kernel_launch(void* const* d_in, const int* in_sizes, int n_in,
                              void* d_out, int out_size, void* d_ws, size_t ws_size,
                              hipStream_t stream) {
  const float* x    = (const float*)d_in[0];
  const int*   mask = (const int*)d_in[1];
  const float* W    = (const float*)d_in[2];
  const float* bias = (const float*)d_in[3];
  const float* cent = (const float*)d_in[4];
  float* out = (float*)d_out;

  const size_t vtmpN = (size_t)BB * KK * DD;
  const size_t ssN   = (size_t)BB * KK;

  const size_t t64   = (size_t)BB * (NN / 64);    // 2048 tiles
  const size_t t128  = (size_t)BB * (NN / 128);   // 1024 tiles
  const size_t need64  = (t64  * KK * DD + t64  * KK + vtmpN + ssN) * sizeof(float);
  const size_t need128 = (t128 * KK * DD + t128 * KK + vtmpN + ssN) * sizeof(float);

  if (ws_size >= need64) {
    float* pv    = (float*)d_ws;
    float* ps    = pv + t64 * KK * DD;
    float* vtmp  = ps + t64 * KK;
    float* ssbuf = vtmp + vtmpN;
    fused_kernel<64><<<(int)t64, 256, 0, stream>>>(x, mask, W, bias, pv, ps, 1);
    finalizeA_kernel<<<BB * KK, 256, 0, stream>>>(pv, ps, cent, vtmp, ssbuf, NN / 64);
    finalizeB_kernel<<<BB, 1024, 0, stream>>>(vtmp, ssbuf, out);
  } else if (ws_size >= need128) {
    float* pv    = (float*)d_ws;
    float* ps    = pv + t128 * KK * DD;
    float* vtmp  = ps + t128 * KK;
    float* ssbuf = vtmp + vtmpN;
    fused_kernel<128><<<(int)t128, 256, 0, stream>>>(x, mask, W, bias, pv, ps, 1);
    finalizeA_kernel<<<BB * KK, 256, 0, stream>>>(pv, ps, cent, vtmp, ssbuf, NN / 128);
    finalizeB_kernel<<<BB, 1024, 0, stream>>>(vtmp, ssbuf, out);
  } else {
    float* vacc  = (float*)d_ws;                 // [BB][KK][DD]
    float* sacc  = vacc + vtmpN;                 // [BB][KK]
    float* vtmp  = sacc + ssN;
    float* ssbuf = vtmp + vtmpN;
    hipMemsetAsync(d_ws, 0, (vtmpN + ssN) * sizeof(float), stream);
    fused_kernel<64><<<(int)t64, 256, 0, stream>>>(x, mask, W, bias, vacc, sacc, 0);
    finalizeA_kernel<<<BB * KK, 256, 0, stream>>>(vacc, sacc, cent, vtmp, ssbuf, 1);
    finalizeB_kernel<<<BB, 1024, 0, stream>>>(vtmp, ssbuf, out);
  }
}

// Round 7
// 63.566 us; speedup vs baseline: 2.2006x; 1.5032x over previous
//
#include <hip/hip_runtime.h>
#include <cstdint>
#include <cstddef>

#define BB 32
#define NN 4096
#define DD 256
#define KK 16

constexpr float FEPS = 1e-12f;

__device__ __forceinline__ float dot4(float4 a, float4 b) {
  return a.x*b.x + a.y*b.y + a.z*b.z + a.w*b.w;
}
__device__ __forceinline__ float4 f4add(float4 a, float4 b) {
  return make_float4(a.x+b.x, a.y+b.y, a.z+b.z, a.w+b.w);
}

// ---------------------------------------------------------------------------
// Fused kernel, TILE tokens per block, 256 threads, 8 blocks/CU (TILE=64).
// Phase A: thread = (token, k-group): KPT logits; x staged via double-buffered
//          16-dim LDS chunks (pad 4->5 float4: <=2-way banks = free).
// Phase B: wave = k-quad over ALL TILE tokens (x re-read hits L1/L2).
// No cross-wave combine; direct partial store.
// ---------------------------------------------------------------------------
template <int TILE>
__global__ __launch_bounds__(256, (TILE == 64 ? 8 : 4)) void fused_kernel(
    const float* __restrict__ x, const int* __restrict__ mask,
    const float* __restrict__ W, const float* __restrict__ bias,
    float* __restrict__ outv, float* __restrict__ outs, int partial_mode)
{
  constexpr int NG    = 256 / TILE;     // k-groups (thread layers)
  constexpr int KPT   = KK / NG;        // k per thread in Phase A
  constexpr int SW4   = TILE / 64;      // staging float4s per thread per chunk
  constexpr int WPG   = 4 / NG;         // waves per k-group
  constexpr int TPBAT = NN / TILE;

  __shared__ float4 xs4[2][TILE * 5];   // 2 x 5*TILE float4 (pad 4->5)
  __shared__ float  al[TILE][KK];
  __shared__ float  psum[TILE][NG];
  __shared__ float  asacc[WPG][KK];

  const int tid  = threadIdx.x;
  const int lane = tid & 63;
  const int wave = tid >> 6;
  const int tok  = tid & (TILE - 1);
  const int kg   = __builtin_amdgcn_readfirstlane(tid / TILE);
  const int slot = __builtin_amdgcn_readfirstlane(wave & (WPG - 1));

  const int tile = blockIdx.x;
  const int b    = tile / TPBAT;
  const int n0   = (tile % TPBAT) * TILE;

  const float4* xb4 = reinterpret_cast<const float4*>(x + ((size_t)b*NN + n0)*DD);
  const int*    mb  = mask + (size_t)b*NN + n0;

  // ---------------- Phase A: KPT logits per thread, dbuf staging ----------
  float part[KPT];
#pragma unroll
  for (int q = 0; q < KPT; ++q) part[q] = bias[kg * KPT + q];

  const int st = tid >> 2;              // staging token (0..63)
  const int sj = tid & 3;               // staging float4 col within chunk

  // prologue: stage chunk 0 into buffer 0
  {
    float4 pre[SW4];
#pragma unroll
    for (int l = 0; l < SW4; ++l)
      pre[l] = xb4[(size_t)(st + l * 64) * 64 + sj];
#pragma unroll
    for (int l = 0; l < SW4; ++l)
      xs4[0][(st + l * 64) * 5 + sj] = pre[l];
  }

#pragma unroll 1
  for (int c = 0; c < 16; ++c) {        // 16 chunks of 16 dims
    __syncthreads();
    const int cur = c & 1;

    float4 nxt[SW4];
    if (c < 15) {
#pragma unroll
      for (int l = 0; l < SW4; ++l)
        nxt[l] = xb4[(size_t)(st + l * 64) * 64 + (c + 1) * 4 + sj];
    }

#pragma unroll
    for (int j = 0; j < 4; ++j) {
      const float4 xv = xs4[cur][tok * 5 + j];
      const float* Wc = W + c * 16 + j * 4;
#pragma unroll
      for (int q = 0; q < KPT; ++q) {
        const float4 wv = *reinterpret_cast<const float4*>(Wc + (kg * KPT + q) * DD);
        part[q] += dot4(xv, wv);
      }
    }

    if (c < 15) {
#pragma unroll
      for (int l = 0; l < SW4; ++l)
        xs4[cur ^ 1][(st + l * 64) * 5 + sj] = nxt[l];
    }
  }

  // masked softmax across NG thread-layers via psum exchange
  float e[KPT], pexp = 0.f;
#pragma unroll
  for (int q = 0; q < KPT; ++q) { e[q] = __expf(part[q]); pexp += e[q]; }
  psum[tok][kg] = pexp;
  __syncthreads();
  float a[KPT];
  {
    float denom = 0.f;
#pragma unroll
    for (int g = 0; g < NG; ++g) denom += psum[tok][g];
    const float r = mb[tok] ? (1.0f / denom) : 0.0f;
#pragma unroll
    for (int q = 0; q < KPT; ++q) a[q] = e[q] * r;
#pragma unroll
    for (int q4 = 0; q4 < KPT; q4 += 4)
      *reinterpret_cast<float4*>(&al[tok][kg * KPT + q4]) =
          make_float4(a[q4], a[q4+1], a[q4+2], a[q4+3]);
  }

  // asum: butterfly over 64 lanes (= 64 distinct tokens per wave)
  {
    float red[KPT];
#pragma unroll
    for (int q = 0; q < KPT; ++q) red[q] = a[q];
#pragma unroll
    for (int off = 32; off >= 1; off >>= 1)
#pragma unroll
      for (int q = 0; q < KPT; ++q) red[q] += __shfl_xor(red[q], off);
    if (lane == 0)
#pragma unroll
      for (int q = 0; q < KPT; ++q) asacc[slot][kg * KPT + q] = red[q];
  }
  __syncthreads();

  // ------ Phase B: wave = k-quad (kq = wave*4), all TILE tokens -----------
  float4 acc0 = make_float4(0.f,0.f,0.f,0.f);
  float4 acc1 = make_float4(0.f,0.f,0.f,0.f);
  float4 acc2 = make_float4(0.f,0.f,0.f,0.f);
  float4 acc3 = make_float4(0.f,0.f,0.f,0.f);

  const float4* xw = xb4 + lane;        // lane owns dims 4*lane..4*lane+3
  const int kq = wave * 4;

#pragma unroll 4
  for (int t = 0; t < TILE; ++t) {
    const float4 xv = xw[(size_t)t * 64];
    const float4 av = *reinterpret_cast<const float4*>(&al[t][kq]);  // broadcast
    acc0.x += av.x*xv.x; acc0.y += av.x*xv.y; acc0.z += av.x*xv.z; acc0.w += av.x*xv.w;
    acc1.x += av.y*xv.x; acc1.y += av.y*xv.y; acc1.z += av.y*xv.z; acc1.w += av.y*xv.w;
    acc2.x += av.z*xv.x; acc2.y += av.z*xv.y; acc2.z += av.z*xv.z; acc2.w += av.z*xv.w;
    acc3.x += av.w*xv.x; acc3.y += av.w*xv.y; acc3.z += av.w*xv.z; acc3.w += av.w*xv.w;
  }

  // ------------- output ----------------------------------------------------
  if (partial_mode) {
    float4* dst = reinterpret_cast<float4*>(outv + (size_t)tile * KK * DD);
    dst[(kq + 0) * 64 + lane] = acc0;
    dst[(kq + 1) * 64 + lane] = acc1;
    dst[(kq + 2) * 64 + lane] = acc2;
    dst[(kq + 3) * 64 + lane] = acc3;
    if (tid < KK) {
      float s = 0.f;
#pragma unroll
      for (int sl = 0; sl < WPG; ++sl) s += asacc[sl][tid];
      outs[tile * KK + tid] = s;
    }
  } else {
    float* vb = outv + (size_t)b * KK * DD;
    const float4 aa[4] = {acc0, acc1, acc2, acc3};
#pragma unroll
    for (int i = 0; i < 4; ++i) {
      float* p = vb + (kq + i) * DD + 4 * lane;
      atomicAdd(p + 0, aa[i].x);
      atomicAdd(p + 1, aa[i].y);
      atomicAdd(p + 2, aa[i].z);
      atomicAdd(p + 3, aa[i].w);
    }
    if (tid < KK) {
      float s = 0.f;
#pragma unroll
      for (int sl = 0; sl < WPG; ++sl) s += asacc[sl][tid];
      atomicAdd(&outs[b * KK + tid], s);
    }
  }
}

// ---------------------------------------------------------------------------
// Finalize A (BB*KK blocks x 256 thr): block = (b,k). float4 slice-sum with
// 4 slice-groups x 4 accumulators, LDS combine, ssum by wave butterfly.
// ---------------------------------------------------------------------------
__global__ __launch_bounds__(256) void finalizeA_kernel(
    const float* __restrict__ pv, const float* __restrict__ ps,
    const float* __restrict__ cent, float* __restrict__ vtmp,
    float* __restrict__ ssbuf, int nslice)
{
  const int blk = blockIdx.x;
  const int b   = blk >> 4;
  const int k   = blk & 15;
  const int tid = threadIdx.x;
  const int sg  = tid >> 6;           // slice group 0..3
  const int ld  = tid & 63;           // float4 dim index

  __shared__ float4 cmbA[3][64];

  // ssum: each wave loads 64-strided slices, butterfly -> all lanes
  float pval = 0.f;
  for (int s = ld; s < nslice; s += 64)
    pval += ps[(size_t)(b * nslice + s) * KK + k];
#pragma unroll
  for (int off = 32; off >= 1; off >>= 1) pval += __shfl_xor(pval, off);
  const float ssum = pval;

  // slice sum: slices s == sg (mod 4), 4 independent accumulators
  const float4* pv4 = reinterpret_cast<const float4*>(pv);
  const size_t base = ((size_t)b * nslice * KK + k) * 64 + ld;  // f4 idx, slice 0
  float4 a0 = make_float4(0.f,0.f,0.f,0.f), a1 = a0, a2 = a0, a3 = a0;
  int s = sg;
  for (; s + 12 < nslice; s += 16) {
    a0 = f4add(a0, pv4[base + (size_t)(s     ) * (KK * 64)]);
    a1 = f4add(a1, pv4[base + (size_t)(s +  4) * (KK * 64)]);
    a2 = f4add(a2, pv4[base + (size_t)(s +  8) * (KK * 64)]);
    a3 = f4add(a3, pv4[base + (size_t)(s + 12) * (KK * 64)]);
  }
  for (; s < nslice; s += 4)
    a0 = f4add(a0, pv4[base + (size_t)s * (KK * 64)]);
  float4 tot = f4add(f4add(a0, a1), f4add(a2, a3));

  if (sg > 0) cmbA[sg - 1][ld] = tot;
  __syncthreads();

  if (sg == 0) {
    tot = f4add(tot, f4add(cmbA[0][ld], f4add(cmbA[1][ld], cmbA[2][ld])));
    const float4 cv = reinterpret_cast<const float4*>(cent)[k * 64 + ld];
    float4 v;
    v.x = tot.x - ssum * cv.x;
    v.y = tot.y - ssum * cv.y;
    v.z = tot.z - ssum * cv.z;
    v.w = tot.w - ssum * cv.w;
    reinterpret_cast<float4*>(vtmp)[((size_t)b * KK + k) * 64 + ld] = v;
    float p = dot4(v, v);
#pragma unroll
    for (int off = 32; off >= 1; off >>= 1) p += __shfl_xor(p, off);
    if (ld == 0) ssbuf[blk] = p;
  }
}

// ---------------------------------------------------------------------------
// Finalize B (BB blocks x 1024 thr): intra-cluster + global L2 normalize.
// ---------------------------------------------------------------------------
__global__ __launch_bounds__(1024) void finalizeB_kernel(
    const float* __restrict__ vtmp, const float* __restrict__ ssbuf,
    float* __restrict__ out)
{
  const int b    = blockIdx.x;
  const int tid  = threadIdx.x;
  const int d    = tid & 255;
  const int kq   = tid >> 8;        // 0..3
  const int lane = tid & 63;
  const int w    = tid >> 6;        // 0..15

  __shared__ float redB[16];
  __shared__ float gsh;

  float u[4];
  float p2 = 0.f;
#pragma unroll
  for (int kk = 0; kk < 4; ++kk) {
    const int k = kq * 4 + kk;
    const float rk = 1.0f / fmaxf(sqrtf(ssbuf[b * KK + k]), FEPS);
    u[kk] = vtmp[((size_t)b * KK + k) * DD + d] * rk;
    p2 += u[kk] * u[kk];
  }
#pragma unroll
  for (int off = 32; off >= 1; off >>= 1) p2 += __shfl_xor(p2, off);
  if (lane == 0) redB[w] = p2;
  __syncthreads();

  if (tid == 0) {
    float g = 0.f;
#pragma unroll
    for (int i = 0; i < 16; ++i) g += redB[i];
    gsh = 1.0f / fmaxf(sqrtf(g), FEPS);
  }
  __syncthreads();

  const float g = gsh;
#pragma unroll
  for (int kk = 0; kk < 4; ++kk) {
    const int k = kq * 4 + kk;
    out[(size_t)b * KK * DD + k * DD + d] = u[kk] * g;
  }
}

extern "C" void kernel_launch(void* const* d_in, const int* in_sizes, int n_in,
                              void* d_out, int out_size, void* d_ws, size_t ws_size,
                              hipStream_t stream) {
  const float* x    = (const float*)d_in[0];
  const int*   mask = (const int*)d_in[1];
  const float* W    = (const float*)d_in[2];
  const float* bias = (const float*)d_in[3];
  const float* cent = (const float*)d_in[4];
  float* out = (float*)d_out;

  const size_t vtmpN = (size_t)BB * KK * DD;
  const size_t ssN   = (size_t)BB * KK;

  const size_t t64   = (size_t)BB * (NN / 64);    // 2048 tiles
  const size_t t128  = (size_t)BB * (NN / 128);   // 1024 tiles
  const size_t need64  = (t64  * KK * DD + t64  * KK + vtmpN + ssN) * sizeof(float);
  const size_t need128 = (t128 * KK * DD + t128 * KK + vtmpN + ssN) * sizeof(float);

  if (ws_size >= need64) {
    float* pv    = (float*)d_ws;
    float* ps    = pv + t64 * KK * DD;
    float* vtmp  = ps + t64 * KK;
    float* ssbuf = vtmp + vtmpN;
    fused_kernel<64><<<(int)t64, 256, 0, stream>>>(x, mask, W, bias, pv, ps, 1);
    finalizeA_kernel<<<BB * KK, 256, 0, stream>>>(pv, ps, cent, vtmp, ssbuf, NN / 64);
    finalizeB_kernel<<<BB, 1024, 0, stream>>>(vtmp, ssbuf, out);
  } else if (ws_size >= need128) {
    float* pv    = (float*)d_ws;
    float* ps    = pv + t128 * KK * DD;
    float* vtmp  = ps + t128 * KK;
    float* ssbuf = vtmp + vtmpN;
    fused_kernel<128><<<(int)t128, 256, 0, stream>>>(x, mask, W, bias, pv, ps, 1);
    finalizeA_kernel<<<BB * KK, 256, 0, stream>>>(pv, ps, cent, vtmp, ssbuf, NN / 128);
    finalizeB_kernel<<<BB, 1024, 0, stream>>>(vtmp, ssbuf, out);
  } else {
    float* vacc  = (float*)d_ws;                 // [BB][KK][DD]
    float* sacc  = vacc + vtmpN;                 // [BB][KK]
    float* vtmp  = sacc + ssN;
    float* ssbuf = vtmp + vtmpN;
    hipMemsetAsync(d_ws, 0, (vtmpN + ssN) * sizeof(float), stream);
    fused_kernel<64><<<(int)t64, 256, 0, stream>>>(x, mask, W, bias, vacc, sacc, 0);
    finalizeA_kernel<<<BB * KK, 256, 0, stream>>>(vacc, sacc, cent, vtmp, ssbuf, 1);
    finalizeB_kernel<<<BB, 1024, 0, stream>>>(vtmp, ssbuf, out);
  }
}